// Round 7
// baseline (241.265 us; speedup 1.0000x reference)
//
#include <hip/hip_runtime.h>

// MassConservingLSTMCell — round 7: 32x32x16 MFMA (2495 TF ceiling vs 2075),
// gates absorbed into the heavy launch, split prep for profiling visibility.
// B=1024, U=256, F=31, D=288 (9 k-chunks of 32).
//
//  k_prepW : 774 blocks — W -> bf16 32x32-fragment images (LDS transpose)
//  k_prepF : 24 blocks  — features -> A images (16) + zero cell_sys (8)
//  k_heavyG: 528 blocks x 256 thr — [0..511]: 64r x 256c x 8u fused R-GEMM;
//            [512..527]: gates (ig,og) for one 64-row stripe.
//  k_final : elementwise combine.
//
// 32x32x16 bf16 layouts (m74/m101-verified C; standard A/B):
//   A[m=lane&31][k=(lane>>5)*8+j]   B[k=(lane>>5)*8+j][n=lane&31]
//   C: col=lane&31, row=(r&3)+8*(r>>2)+4*(lane>>5), r in [0,16)

#define EPS_L1 1e-7f

constexpr int BB  = 1024;
constexpr int U   = 256;
constexpr int F   = 31;
constexpr int D   = 1 + U + F;      // 288
constexpr int NBV = BB * U;         // 262144
constexpr int NCH = D / 32;         // 9
constexpr int UIMGB = NCH * 16384;  // 147456 B per u-slice B-image
constexpr size_t WTB_BYTES  = (size_t)258 * UIMGB;
constexpr size_t FEAT_BYTES = (size_t)BB * D * 2;
constexpr int PITCH = 260;

typedef float f32x16 __attribute__((ext_vector_type(16)));
typedef short bf16x8 __attribute__((ext_vector_type(8)));

__device__ __forceinline__ unsigned f2bf(float x) {
  union { float f; unsigned u; } v; v.f = x;
  unsigned r = v.u + 0x7FFFu + ((v.u >> 16) & 1u);
  return r >> 16;
}

#define GLDS16(gp, lp)                                                        \
  __builtin_amdgcn_global_load_lds(                                          \
      (const __attribute__((address_space(1))) void*)(gp),                   \
      (__attribute__((address_space(3))) void*)(lp), 16, 0, 0)

#define MFMA32(a, b, c) __builtin_amdgcn_mfma_f32_32x32x16_bf16((a), (b), (c), 0, 0, 0)

// ---------------------------------------------------------------- k_prepW
// Image region (u, c, n0) with n0 = nt*2+h (nt 0..7 col-32-group, h 0..1 k16):
// lane l, j: W[k = c*32 + h*16 + (l>>5)*8 + j][col = nt*32 + (l&31)], 1KB/region.
__global__ __launch_bounds__(256) void k_prepW(
    const float* __restrict__ Wi, const float* __restrict__ Wr,
    const float* __restrict__ Wo, short* __restrict__ WtB) {
  __shared__ short lds[2][32 * PITCH];
  const int bid = blockIdx.x, t = threadIdx.x;
  const int u = bid / 3, part = bid % 3;
  const float* src; long ld;
  if (u < 256)       { src = Wr + (size_t)u * 256; ld = 65536; }
  else if (u == 256) { src = Wi; ld = 256; }
  else               { src = Wo; ld = 256; }
  short* dst = WtB + (size_t)u * 73728;
  const int lane = t & 63, wave = t >> 6;
  const int g2 = lane >> 5, l31 = lane & 31;

#pragma unroll
  for (int cc = 0; cc < 3; ++cc) {
    const int c = part * 3 + cc;
    short* buf = lds[cc & 1];
#pragma unroll
    for (int i = 0; i < 8; ++i) {
      const int f = i * 256 + t;
      const int row = f >> 6, col4 = f & 63;
      const float4 v = *(const float4*)(src + (size_t)(c * 32 + row) * ld + col4 * 4);
      const unsigned lo = f2bf(v.x) | (f2bf(v.y) << 16);
      const unsigned hi = f2bf(v.z) | (f2bf(v.w) << 16);
      unsigned* wp = (unsigned*)&buf[row * PITCH + col4 * 4];
      wp[0] = lo; wp[1] = hi;
    }
    __syncthreads();
#pragma unroll
    for (int i = 0; i < 4; ++i) {
      const int n0 = wave * 4 + i;
      const int nt = n0 >> 1, h = n0 & 1;
      bf16x8 hv;
#pragma unroll
      for (int j = 0; j < 8; ++j)
        hv[j] = buf[(h * 16 + g2 * 8 + j) * PITCH + nt * 32 + l31];
      *(bf16x8*)(dst + (size_t)(c * 16 + n0) * 512 + lane * 8) = hv;
    }
    __syncthreads();
  }
}

// ---------------------------------------------------------------- k_prepF
// A-image region reg = c*4 + (mt*2+h): lane l, j:
//   feat[row = mt*32 + (l&31)][k = c*32 + h*16 + (l>>5)*8 + j]
__global__ __launch_bounds__(256) void k_prepF(
    const float* __restrict__ lc, const float* __restrict__ p,
    const float* __restrict__ other, short* __restrict__ featImg,
    float* __restrict__ cell_sys) {
  __shared__ float inv_s[64];
  const int bid = blockIdx.x, t = threadIdx.x;
  if (bid < 16) {
    const int b0 = bid * 64;
    const int row = t >> 2, q = t & 3;
    const float4* lp = (const float4*)(lc + (size_t)(b0 + row) * 256 + q * 64);
    float s = 0.f;
#pragma unroll
    for (int j = 0; j < 16; ++j) {
      const float4 v = lp[j];
      s += fabsf(v.x) + fabsf(v.y) + fabsf(v.z) + fabsf(v.w);
    }
    s += __shfl_xor(s, 1, 64);
    s += __shfl_xor(s, 2, 64);
    if (q == 0) inv_s[row] = 1.f / (s + EPS_L1);
    __syncthreads();
#pragma unroll
    for (int i = 0; i < 9; ++i) {
      const int idx = i * 256 + t;
      const int reg = idx >> 6, l = idx & 63;
      const int c = reg >> 2, sub = reg & 3;
      const int mt = sub >> 1, h = sub & 1;
      const int lrow = mt * 32 + (l & 31);
      const int grow = b0 + lrow;
      const int k0 = c * 32 + h * 16 + (l >> 5) * 8;
      bf16x8 hv;
#pragma unroll
      for (int j = 0; j < 8; ++j) {
        const int k = k0 + j;
        float v;
        if (k == 0) v = p[grow];
        else if (k <= 256) v = lc[(size_t)grow * 256 + (k - 1)] * inv_s[lrow];
        else v = other[(size_t)grow * 31 + (k - 257)];
        hv[j] = (short)f2bf(v);
      }
      *(bf16x8*)(featImg + (size_t)bid * 18432 + (size_t)reg * 512 + l * 8) = hv;
    }
  } else {
    float4* cs4 = (float4*)cell_sys;
    const int base = (bid - 16) * 8192 + t;
    const float4 z = {0.f, 0.f, 0.f, 0.f};
#pragma unroll
    for (int k2 = 0; k2 < 32; ++k2) cs4[base + k2 * 256] = z;
  }
}

// ---------------------------------------------------------------- k_heavyG
// bid<512: heavy. Block 64r x 256c x 8u; 4 waves = col quarters (cq*64).
// Wave tile: 2mt(32r) x 2nt(32c), acc/outa = 2x2 f32x16.
// bid>=512: gates for 64-row stripe (mb = bid-512), Wi/Wo images 256/257.
__global__ __launch_bounds__(256, 2) void k_heavyG(
    const short* __restrict__ featImg, const short* __restrict__ WtB,
    const float* __restrict__ lc, const float* __restrict__ br,
    const float* __restrict__ bi, const float* __restrict__ bo,
    float* __restrict__ cell_sys, float* __restrict__ dout) {
  __shared__ short aT[18432];          // 36864 B: [c][sub][1KB]
  __shared__ float rsum[2][64][4];
  __shared__ float lcs[2][64];

  const int t = threadIdx.x, lane = t & 63, cq = t >> 6;
  const int g2 = lane >> 5, l31 = lane & 31;
  const int bid = blockIdx.x;
  const bool is_gate = bid >= 512;
  const int Mb = is_gate ? (bid - 512) : ((bid >> 3) & 15);
  const int ug = is_gate ? 0 : ((bid & 7) * 4 + (bid >> 7));
  const int b0 = Mb * 64;
  const int u0 = ug * 8;

  // stage A image (36864 B, linear)
  {
    const char* gA = (const char*)featImg + (size_t)Mb * 36864;
    char* lA = (char*)aT;
#pragma unroll
    for (int i = 0; i < 9; ++i)
      GLDS16(gA + i * 4096 + t * 16, lA + i * 4096 + t * 16);
  }

  const char* aB = (const char*)aT + lane * 16;     // + c*4096 + sub*1024
  const char* bB = (const char*)WtB +
      (is_gate ? (size_t)256 * UIMGB : (size_t)u0 * UIMGB) +
      cq * 4096 + lane * 16;                        // + c*16384 + fr*1024

  f32x16 acc[2][2];
#pragma unroll
  for (int m = 0; m < 2; ++m)
#pragma unroll
    for (int n = 0; n < 2; ++n)
#pragma unroll
      for (int r = 0; r < 16; ++r) acc[m][n][r] = 0.f;

  // B dist-2 prefetch: 3-slot rotation of 4 frags (nt*2+h)
  bf16x8 bfr[3][4];
#pragma unroll
  for (int q = 0; q < 4; ++q) bfr[0][q] = *(const bf16x8*)(bB + q * 1024);
#pragma unroll
  for (int q = 0; q < 4; ++q) bfr[1][q] = *(const bf16x8*)(bB + 16384 + q * 1024);

  __syncthreads();   // A resident

  // A dist-1 prefetch: 2-slot rotation of 4 frags (mt*2+h)
  bf16x8 afr[2][4];
#pragma unroll
  for (int q = 0; q < 4; ++q) afr[0][q] = *(const bf16x8*)(aB + q * 1024);

  if (!is_gate) {
    f32x16 outa[2][2];
#pragma unroll
    for (int m = 0; m < 2; ++m)
#pragma unroll
      for (int n = 0; n < 2; ++n)
#pragma unroll
        for (int r = 0; r < 16; ++r) outa[m][n][r] = 0.f;

    for (int uu = 0; uu < 8; ++uu) {
      const int u = u0 + uu;
      float bv[2];
#pragma unroll
      for (int n = 0; n < 2; ++n)
        bv[n] = br[(size_t)u * 256 + cq * 64 + n * 32 + l31];
      if (t < 64) lcs[uu & 1][t] = lc[(size_t)(b0 + t) * 256 + u];

#pragma unroll
      for (int c = 0; c < 9; ++c) {
#pragma unroll
        for (int q = 0; q < 4; ++q)
          bfr[(c + 2) % 3][q] = *(const bf16x8*)(bB + (c + 2) * 16384 + q * 1024);
        if (c < 8) {
#pragma unroll
          for (int q = 0; q < 4; ++q)
            afr[(c + 1) & 1][q] = *(const bf16x8*)(aB + (c + 1) * 4096 + q * 1024);
        }
        const int as = c & 1, bs = c % 3;
#pragma unroll
        for (int m = 0; m < 2; ++m)
#pragma unroll
          for (int n = 0; n < 2; ++n) {
            acc[m][n] = MFMA32(afr[as][m * 2],     bfr[bs][n * 2],     acc[m][n]);
            acc[m][n] = MFMA32(afr[as][m * 2 + 1], bfr[bs][n * 2 + 1], acc[m][n]);
          }
      }
      bB += UIMGB;
#pragma unroll
      for (int q = 0; q < 4; ++q) afr[0][q] = *(const bf16x8*)(aB + q * 1024);

      // ---- epilogue: bias+relu (into acc), rownorm, weighted accumulate
      const int ub = uu & 1;
      float sm[2][16];
#pragma unroll
      for (int m = 0; m < 2; ++m)
#pragma unroll
        for (int r = 0; r < 16; ++r) {
          const float r0v = fmaxf(acc[m][0][r] + bv[0], 0.f);
          const float r1v = fmaxf(acc[m][1][r] + bv[1], 0.f);
          acc[m][0][r] = r0v; acc[m][1][r] = r1v;
          sm[m][r] = r0v + r1v;
        }
#pragma unroll
      for (int msk = 1; msk < 32; msk <<= 1)
#pragma unroll
        for (int m = 0; m < 2; ++m)
#pragma unroll
          for (int r = 0; r < 16; ++r)
            sm[m][r] += __shfl_xor(sm[m][r], msk, 64);
      if (l31 == 0) {
#pragma unroll
        for (int m = 0; m < 2; ++m)
#pragma unroll
          for (int r = 0; r < 16; ++r)
            rsum[ub][m * 32 + (r & 3) + 8 * (r >> 2) + 4 * g2][cq] = sm[m][r];
      }
      __syncthreads();
#pragma unroll
      for (int m = 0; m < 2; ++m)
#pragma unroll
        for (int r = 0; r < 16; ++r) {
          const int row = m * 32 + (r & 3) + 8 * (r >> 2) + 4 * g2;
          const float4 rv = *(const float4*)&rsum[ub][row][0];
          const float tot = (rv.x + rv.y) + (rv.z + rv.w);
          const float alpha = lcs[ub][row] * __builtin_amdgcn_rcpf(tot);
          outa[m][0][r] = fmaf(alpha, acc[m][0][r], outa[m][0][r]);
          outa[m][1][r] = fmaf(alpha, acc[m][1][r], outa[m][1][r]);
          acc[m][0][r] = 0.f;
          acc[m][1][r] = 0.f;
        }
    }

#pragma unroll
    for (int m = 0; m < 2; ++m)
#pragma unroll
      for (int r = 0; r < 16; ++r) {
        const int grow = b0 + m * 32 + (r & 3) + 8 * (r >> 2) + 4 * g2;
#pragma unroll
        for (int n = 0; n < 2; ++n)
          atomicAdd(&cell_sys[(size_t)grow * 256 + cq * 64 + n * 32 + l31],
                    outa[m][n][r]);
      }
  } else {
    // ================= gates path: g=0 (ig, Wi img 256), g=1 (og, Wo img 257)
#pragma unroll
    for (int g = 0; g < 2; ++g) {
      const float* bias = (g == 0) ? bi : bo;
      float bv[2];
#pragma unroll
      for (int n = 0; n < 2; ++n) bv[n] = bias[cq * 64 + n * 32 + l31];

#pragma unroll
      for (int c = 0; c < 9; ++c) {
#pragma unroll
        for (int q = 0; q < 4; ++q)
          bfr[(c + 2) % 3][q] = *(const bf16x8*)(bB + (c + 2) * 16384 + q * 1024);
        if (c < 8) {
#pragma unroll
          for (int q = 0; q < 4; ++q)
            afr[(c + 1) & 1][q] = *(const bf16x8*)(aB + (c + 1) * 4096 + q * 1024);
        }
        const int as = c & 1, bs = c % 3;
#pragma unroll
        for (int m = 0; m < 2; ++m)
#pragma unroll
          for (int n = 0; n < 2; ++n) {
            acc[m][n] = MFMA32(afr[as][m * 2],     bfr[bs][n * 2],     acc[m][n]);
            acc[m][n] = MFMA32(afr[as][m * 2 + 1], bfr[bs][n * 2 + 1], acc[m][n]);
          }
      }
      bB += UIMGB;
#pragma unroll
      for (int q = 0; q < 4; ++q) afr[0][q] = *(const bf16x8*)(aB + q * 1024);

      // sigmoid
#pragma unroll
      for (int m = 0; m < 2; ++m)
#pragma unroll
        for (int n = 0; n < 2; ++n)
#pragma unroll
          for (int r = 0; r < 16; ++r)
            acc[m][n][r] = 1.f / (1.f + __expf(-(acc[m][n][r] + bv[n])));

      if (g == 0) {
        float sm[2][16];
#pragma unroll
        for (int m = 0; m < 2; ++m)
#pragma unroll
          for (int r = 0; r < 16; ++r) sm[m][r] = acc[m][0][r] + acc[m][1][r];
#pragma unroll
        for (int msk = 1; msk < 32; msk <<= 1)
#pragma unroll
          for (int m = 0; m < 2; ++m)
#pragma unroll
            for (int r = 0; r < 16; ++r)
              sm[m][r] += __shfl_xor(sm[m][r], msk, 64);
        if (l31 == 0) {
#pragma unroll
          for (int m = 0; m < 2; ++m)
#pragma unroll
            for (int r = 0; r < 16; ++r)
              rsum[0][m * 32 + (r & 3) + 8 * (r >> 2) + 4 * g2][cq] = sm[m][r];
        }
        __syncthreads();
#pragma unroll
        for (int m = 0; m < 2; ++m)
#pragma unroll
          for (int r = 0; r < 16; ++r) {
            const int row = m * 32 + (r & 3) + 8 * (r >> 2) + 4 * g2;
            const float4 rv = *(const float4*)&rsum[0][row][0];
            const float inv = 1.f / ((rv.x + rv.y) + (rv.z + rv.w));
#pragma unroll
            for (int n = 0; n < 2; ++n) {
              dout[(size_t)(b0 + row) * 256 + cq * 64 + n * 32 + l31] =
                  acc[m][n][r] * inv;
              acc[m][n][r] = 0.f;
            }
          }
      } else {
#pragma unroll
        for (int m = 0; m < 2; ++m)
#pragma unroll
          for (int r = 0; r < 16; ++r) {
            const int row = m * 32 + (r & 3) + 8 * (r >> 2) + 4 * g2;
#pragma unroll
            for (int n = 0; n < 2; ++n)
              dout[(size_t)NBV + (size_t)(b0 + row) * 256 + cq * 64 + n * 32 + l31] =
                  acc[m][n][r];
          }
      }
    }
  }
}

// ---------------------------------------------------------------- k_final
__global__ __launch_bounds__(256) void k_final(
    const float* __restrict__ cell_sys, const float* __restrict__ p,
    float* __restrict__ d_out) {
  const int i = blockIdx.x * 256 + threadIdx.x;
  const float ig = d_out[i];
  const float ogv = d_out[NBV + i];
  const float cand = fmaf(ig, p[i >> 8], cell_sys[i]);
  const float outp = ogv * cand;
  d_out[i] = (1.0f - ogv) * cand;
  d_out[NBV + i] = outp;
}

// ---------------------------------------------------------------- launch
extern "C" void kernel_launch(void* const* d_in, const int* in_sizes, int n_in,
                              void* d_out, int out_size, void* d_ws, size_t ws_size,
                              hipStream_t stream) {
  const float* lc    = (const float*)d_in[0];
  const float* p     = (const float*)d_in[1];
  const float* other = (const float*)d_in[2];
  const float* Wi    = (const float*)d_in[3];
  const float* bi    = (const float*)d_in[4];
  const float* Wr    = (const float*)d_in[5];
  const float* br    = (const float*)d_in[6];
  const float* Wo    = (const float*)d_in[7];
  const float* bo    = (const float*)d_in[8];
  float* out = (float*)d_out;

  char* wsb = (char*)d_ws;
  short* WtB      = (short*)wsb;
  short* featImg  = (short*)(wsb + WTB_BYTES);
  float* cell_sys = (float*)(wsb + WTB_BYTES + FEAT_BYTES);

  k_prepW<<<774, 256, 0, stream>>>(Wi, Wr, Wo, WtB);
  k_prepF<<<24, 256, 0, stream>>>(lc, p, other, featImg, cell_sys);
  k_heavyG<<<528, 256, 0, stream>>>(featImg, WtB, lc, br, bi, bo, cell_sys, out);
  k_final<<<1024, 256, 0, stream>>>(cell_sys, p, out);
}